// Round 1
// baseline (1279.614 us; speedup 1.0000x reference)
//
#include <hip/hip_runtime.h>

#define HH 512
#define WW 512
#define BATCH 32
#define NPIX (BATCH*HH*WW)

__device__ __forceinline__ float softplus_pos(float x) { // softplus(x)
    return fmaxf(x, 0.0f) + log1pf(expf(-fabsf(x)));
}

__global__ void init_acc(double* acc) {
    if (threadIdx.x < 8) acc[threadIdx.x] = 0.0;
}

// edge = t * (1 - erode3x3(t)), zero-padded erosion
__global__ void edge_kernel(const float* __restrict__ t, unsigned char* __restrict__ edge) {
    int idx = blockIdx.x * blockDim.x + threadIdx.x;
    if (idx >= NPIX) return;
    int x = idx & (WW - 1);
    int y = (idx >> 9) & (HH - 1);
    float tv = t[idx];
    unsigned char e = 0;
    if (tv > 0.5f) {
        float mn = 1.0f;
        #pragma unroll
        for (int dy = -1; dy <= 1; ++dy) {
            #pragma unroll
            for (int dx = -1; dx <= 1; ++dx) {
                int yy = y + dy, xx = x + dx;
                float v = (yy >= 0 && yy < HH && xx >= 0 && xx < WW) ? t[idx + dy * WW + dx] : 0.0f;
                mn = fminf(mn, v);
            }
        }
        e = (mn < 0.5f) ? 1 : 0;
    }
    edge[idx] = e;
}

// bmask = dilate3x3(edge), zero-padded
__global__ void bmask_kernel(const unsigned char* __restrict__ edge, unsigned char* __restrict__ bmask) {
    int idx = blockIdx.x * blockDim.x + threadIdx.x;
    if (idx >= NPIX) return;
    int x = idx & (WW - 1);
    int y = (idx >> 9) & (HH - 1);
    unsigned char mx = 0;
    #pragma unroll
    for (int dy = -1; dy <= 1; ++dy) {
        #pragma unroll
        for (int dx = -1; dx <= 1; ++dx) {
            int yy = y + dy, xx = x + dx;
            if (yy >= 0 && yy < HH && xx >= 0 && xx < WW) {
                mx |= edge[idx + dy * WW + dx];
            }
        }
    }
    bmask[idx] = mx;
}

// Fused: all reductions in one streaming pass.
// acc[0]=sum(p) acc[1]=sum(t) acc[2]=sum(p*t) acc[3]=sum(focal_el) acc[4]=sum(bce_el) acc[5]=sum(bnd*w)
__global__ void main_kernel(const float* __restrict__ xin, const float* __restrict__ tin,
                            const unsigned char* __restrict__ bmask,
                            const float* __restrict__ alpha_p, const float* __restrict__ gamma_p,
                            double* __restrict__ acc) {
    const float a = fminf(fmaxf(alpha_p[0], 0.1f), 0.9f);
    const float g = fminf(fmaxf(gamma_p[0], 1.0f), 5.0f);
    const float SQ2 = 1.4142135f;
    const float INFD = 10000.0f;

    double s_p = 0.0, s_t = 0.0, s_pt = 0.0, s_f = 0.0, s_b = 0.0, s_bnd = 0.0;

    for (int idx = blockIdx.x * blockDim.x + threadIdx.x; idx < NPIX; idx += gridDim.x * blockDim.x) {
        float xv = xin[idx];
        float tv = tin[idx];
        float p = 1.0f / (1.0f + expf(-xv));
        float l1pe = log1pf(expf(-fabsf(xv)));
        float sp_neg = fmaxf(-xv, 0.0f) + l1pe;  // softplus(-x)
        float sp_pos = fmaxf(xv, 0.0f) + l1pe;   // softplus(x)

        float st = tv * 0.95f + 0.025f;
        float bce_el = st * sp_neg + (1.0f - st) * sp_pos;
        float p_t = st * p + (1.0f - st) * (1.0f - p);
        float a_t = st * a + (1.0f - st) * (1.0f - a);
        float focal_el = a_t * powf(1.0f - p_t, g) * bce_el;

        float bce2 = 7.0f * tv * sp_neg + (1.0f - tv) * sp_pos;

        // ---- boundary weight via exact truncated chamfer (ring search) ----
        int x0 = idx & (WW - 1);
        int y0 = (idx >> 9) & (HH - 1);
        int base = idx - y0 * WW - x0;   // start of this image
        float d;
        if (bmask[idx]) {
            d = 0.0f;
        } else {
            float best = INFD;
            for (int r = 1; r <= 24; ++r) {
                if (best <= (float)r) break;
                int ylo = y0 - r, yhi = y0 + r;
                // top & bottom rows of ring
                for (int dx = -r; dx <= r; ++dx) {
                    int xx = x0 + dx;
                    if (xx < 0 || xx >= WW) continue;
                    int mn = abs(dx);
                    float cost = (float)(r - mn) + SQ2 * (float)mn;
                    if (cost < best) {
                        bool hit = false;
                        if (ylo >= 0 && bmask[base + ylo * WW + xx]) hit = true;
                        if (yhi < HH && bmask[base + yhi * WW + xx]) hit = true;
                        if (hit) best = cost;
                    }
                }
                // left & right columns (excluding corners)
                int xlo = x0 - r, xhi = x0 + r;
                for (int dy = -r + 1; dy <= r - 1; ++dy) {
                    int yy = y0 + dy;
                    if (yy < 0 || yy >= HH) continue;
                    int mn = abs(dy);
                    float cost = (float)(r - mn) + SQ2 * (float)mn;
                    if (cost < best) {
                        bool hit = false;
                        if (xlo >= 0 && bmask[base + yy * WW + xlo]) hit = true;
                        if (xhi < WW && bmask[base + yy * WW + xhi]) hit = true;
                        if (hit) best = cost;
                    }
                }
            }
            d = best;
        }
        float wgt = expf(-d * (1.0f / 3.0f)) + 0.1f;

        float pc = fminf(fmaxf(p, 1e-7f), 1.0f - 1e-7f);
        float bnd = -(tv * logf(pc) + (1.0f - tv) * log1pf(-pc));

        s_p  += (double)p;
        s_t  += (double)tv;
        s_pt += (double)(p * tv);
        s_f  += (double)focal_el;
        s_b  += (double)bce2;
        s_bnd += (double)(bnd * wgt);
    }

    // wave (64-lane) shuffle reduction
    #pragma unroll
    for (int off = 32; off > 0; off >>= 1) {
        s_p   += __shfl_down(s_p, off);
        s_t   += __shfl_down(s_t, off);
        s_pt  += __shfl_down(s_pt, off);
        s_f   += __shfl_down(s_f, off);
        s_b   += __shfl_down(s_b, off);
        s_bnd += __shfl_down(s_bnd, off);
    }
    if ((threadIdx.x & 63) == 0) {
        atomicAdd(&acc[0], s_p);
        atomicAdd(&acc[1], s_t);
        atomicAdd(&acc[2], s_pt);
        atomicAdd(&acc[3], s_f);
        atomicAdd(&acc[4], s_b);
        atomicAdd(&acc[5], s_bnd);
    }
}

__global__ void finalize_kernel(const double* __restrict__ acc, float* __restrict__ out) {
    if (threadIdx.x == 0 && blockIdx.x == 0) {
        double S_p = acc[0], S_t = acc[1], S_pt = acc[2];
        double S_f = acc[3], S_b = acc[4], S_bnd = acc[5];
        const double N = (double)NPIX;
        double inter = S_pt;
        double card = S_p + S_t;
        double dice_score = (2.0 * inter + 1e-6) / fmax(card + 1e-6, 1e-7);
        double dice = (S_t > 0.0) ? (1.0 - dice_score) : 0.0;
        double focal = S_f / N;
        double bce = S_b / N;
        double pos_ratio = S_t / N;
        double da = 0.7 * (1.0 + pos_ratio);
        double db = 0.3 * (2.0 - pos_ratio);
        double fn = S_t - S_pt;
        double fp = (S_p - S_pt) * 3.0;
        double tversky = 1.0 - (S_pt + 1e-6) / (S_pt + da * fn + db * fp + 1e-6);
        double bnd = S_bnd / N;
        out[0] = (float)(0.35 * dice + 0.25 * focal + 0.15 * bce + 0.15 * tversky + 0.1 * bnd);
    }
}

extern "C" void kernel_launch(void* const* d_in, const int* in_sizes, int n_in,
                              void* d_out, int out_size, void* d_ws, size_t ws_size,
                              hipStream_t stream) {
    const float* inputs  = (const float*)d_in[0];
    const float* targets = (const float*)d_in[1];
    const float* alpha_p = (const float*)d_in[2];
    const float* gamma_p = (const float*)d_in[3];
    float* out = (float*)d_out;

    char* ws = (char*)d_ws;
    double* acc = (double*)ws;                         // 64 B
    unsigned char* edge  = (unsigned char*)(ws + 64);            // NPIX bytes
    unsigned char* bmask = (unsigned char*)(ws + 64 + NPIX);     // NPIX bytes

    init_acc<<<1, 64, 0, stream>>>(acc);

    int threads = 256;
    int blocks_px = (NPIX + threads - 1) / threads;
    edge_kernel<<<blocks_px, threads, 0, stream>>>(targets, edge);
    bmask_kernel<<<blocks_px, threads, 0, stream>>>(edge, bmask);

    main_kernel<<<4096, threads, 0, stream>>>(inputs, targets, bmask, alpha_p, gamma_p, acc);

    finalize_kernel<<<1, 64, 0, stream>>>(acc, out);
}

// Round 2
// 127.746 us; speedup vs baseline: 10.0169x; 10.0169x over previous
//
#include <hip/hip_runtime.h>

#define HH 512
#define WW 512
#define BATCH 32
#define NPIX (BATCH*HH*WW)
#define NQ (NPIX/4)
#define MAIN_BLOCKS 2048
#define MAIN_THREADS 256

// ---------------- fused edge + bmask (LDS-tiled, one global pass) ----------------
// edge = t * (1 - erode3x3(t)) ; bmask = dilate3x3(edge) ; zero padding everywhere.
__global__ __launch_bounds__(256) void bmask_fused_kernel(const float* __restrict__ t,
                                                          unsigned char* __restrict__ bmask) {
    __shared__ float st[36][36];
    __shared__ unsigned char se[36][36];
    const int b = blockIdx.z;
    const int tx0 = blockIdx.x * 32, ty0 = blockIdx.y * 32;
    const float* timg = t + b * HH * WW;

    for (int i = threadIdx.x; i < 36 * 36; i += 256) {
        int ly = i / 36, lx = i % 36;
        int gy = ty0 - 2 + ly, gx = tx0 - 2 + lx;
        float v = (gy >= 0 && gy < HH && gx >= 0 && gx < WW) ? timg[gy * WW + gx] : 0.0f;
        st[ly][lx] = v;
    }
    __syncthreads();

    for (int i = threadIdx.x; i < 34 * 34; i += 256) {
        int ly = i / 34 + 1, lx = i % 34 + 1;
        float tv = st[ly][lx];
        unsigned char e = 0;
        if (tv > 0.5f) {
            float mn = 1e9f;
            #pragma unroll
            for (int dy = -1; dy <= 1; ++dy)
                #pragma unroll
                for (int dx = -1; dx <= 1; ++dx)
                    mn = fminf(mn, st[ly + dy][lx + dx]);
            e = (mn < 0.5f) ? 1 : 0;
        }
        se[ly][lx] = e;
    }
    __syncthreads();

    for (int i = threadIdx.x; i < 32 * 32; i += 256) {
        int oy = i / 32, ox = i % 32;
        unsigned char m = 0;
        #pragma unroll
        for (int dy = -1; dy <= 1; ++dy)
            #pragma unroll
            for (int dx = -1; dx <= 1; ++dx)
                m |= se[1 + oy + dy + 1][1 + ox + dx + 1];
        bmask[b * HH * WW + (ty0 + oy) * WW + tx0 + ox] = m;
    }
}

// ---------------- fused streaming reductions (no global atomics) ----------------
// partials[blockIdx*6 + i]: 0=sum(p) 1=sum(t) 2=sum(p*t) 3=sum(focal) 4=sum(bce) 5=sum(bnd*w)
__global__ __launch_bounds__(MAIN_THREADS) void main_kernel(
        const float4* __restrict__ x4, const float4* __restrict__ t4,
        const unsigned char* __restrict__ bmask,
        const float* __restrict__ alpha_p, const float* __restrict__ gamma_p,
        double* __restrict__ partials) {
    const float a = fminf(fmaxf(alpha_p[0], 0.1f), 0.9f);
    const float g = fminf(fmaxf(gamma_p[0], 1.0f), 5.0f);
    const float SQ2 = 1.4142135f;
    const float INFD = 10000.0f;
    const float LOGCLIP = 16.11809565f;   // -log(1e-7)

    double s_p = 0.0, s_t = 0.0, s_pt = 0.0, s_f = 0.0, s_b = 0.0, s_bnd = 0.0;

    for (int q = blockIdx.x * MAIN_THREADS + threadIdx.x; q < NQ; q += gridDim.x * MAIN_THREADS) {
        float4 xv4 = x4[q];
        float4 tv4 = t4[q];
        unsigned int bm4 = ((const unsigned int*)bmask)[q];
        int pix0 = q * 4;
        float xs[4] = {xv4.x, xv4.y, xv4.z, xv4.w};
        float ts[4] = {tv4.x, tv4.y, tv4.z, tv4.w};

        #pragma unroll
        for (int k = 0; k < 4; ++k) {
            float xv = xs[k];
            float tv = ts[k];
            unsigned char bm = (bm4 >> (8 * k)) & 0xff;
            int pix = pix0 + k;

            float p = 1.0f / (1.0f + expf(-xv));
            float l1pe = log1pf(expf(-fabsf(xv)));
            float sp_neg = fmaxf(-xv, 0.0f) + l1pe;  // softplus(-x) = -log(p)
            float sp_pos = fmaxf(xv, 0.0f) + l1pe;   // softplus(x)  = -log(1-p)

            float st = tv * 0.95f + 0.025f;
            float bce_el = st * sp_neg + (1.0f - st) * sp_pos;
            float p_t = st * p + (1.0f - st) * (1.0f - p);
            float a_t = st * a + (1.0f - st) * (1.0f - a);
            float u = 1.0f - p_t;                       // in (0,1)
            float focal_el = a_t * exp2f(g * log2f(u)) * bce_el;

            float bce2 = 7.0f * tv * sp_neg + (1.0f - tv) * sp_pos;

            // boundary weight via exact truncated chamfer (early-exit ring search)
            float d;
            if (bm) {
                d = 0.0f;
            } else {
                int x0 = pix & (WW - 1);
                int y0 = (pix >> 9) & (HH - 1);
                int base = pix - y0 * WW - x0;
                float best = INFD;
                for (int r = 1; r <= 24; ++r) {
                    if (best <= (float)r) break;
                    int ylo = y0 - r, yhi = y0 + r;
                    for (int dx = -r; dx <= r; ++dx) {
                        int xx = x0 + dx;
                        if (xx < 0 || xx >= WW) continue;
                        int mn = abs(dx);
                        float cost = (float)(r - mn) + SQ2 * (float)mn;
                        if (cost < best) {
                            bool hit = false;
                            if (ylo >= 0 && bmask[base + ylo * WW + xx]) hit = true;
                            if (yhi < HH && bmask[base + yhi * WW + xx]) hit = true;
                            if (hit) best = cost;
                        }
                    }
                    int xlo = x0 - r, xhi = x0 + r;
                    for (int dy = -r + 1; dy <= r - 1; ++dy) {
                        int yy = y0 + dy;
                        if (yy < 0 || yy >= HH) continue;
                        int mn = abs(dy);
                        float cost = (float)(r - mn) + SQ2 * (float)mn;
                        if (cost < best) {
                            bool hit = false;
                            if (xlo >= 0 && bmask[base + yy * WW + xlo]) hit = true;
                            if (xhi < WW && bmask[base + yy * WW + xhi]) hit = true;
                            if (hit) best = cost;
                        }
                    }
                }
                d = best;
            }
            float wgt = expf(-d * (1.0f / 3.0f)) + 0.1f;

            // bnd_bce with clip(p,1e-7,1-1e-7) == clamp softplus at -log(1e-7)
            float bnd = tv * fminf(sp_neg, LOGCLIP) + (1.0f - tv) * fminf(sp_pos, LOGCLIP);

            s_p   += (double)p;
            s_t   += (double)tv;
            s_pt  += (double)(p * tv);
            s_f   += (double)focal_el;
            s_b   += (double)bce2;
            s_bnd += (double)(bnd * wgt);
        }
    }

    // wave (64-lane) shuffle reduction
    #pragma unroll
    for (int off = 32; off > 0; off >>= 1) {
        s_p   += __shfl_down(s_p, off);
        s_t   += __shfl_down(s_t, off);
        s_pt  += __shfl_down(s_pt, off);
        s_f   += __shfl_down(s_f, off);
        s_b   += __shfl_down(s_b, off);
        s_bnd += __shfl_down(s_bnd, off);
    }

    __shared__ double red[4][6];
    int lane = threadIdx.x & 63, wid = threadIdx.x >> 6;
    if (lane == 0) {
        red[wid][0] = s_p;  red[wid][1] = s_t;  red[wid][2] = s_pt;
        red[wid][3] = s_f;  red[wid][4] = s_b;  red[wid][5] = s_bnd;
    }
    __syncthreads();
    if (threadIdx.x == 0) {
        double o[6];
        #pragma unroll
        for (int i = 0; i < 6; ++i)
            o[i] = red[0][i] + red[1][i] + red[2][i] + red[3][i];
        #pragma unroll
        for (int i = 0; i < 6; ++i)
            partials[blockIdx.x * 6 + i] = o[i];
    }
}

// ---------------- final reduction + loss assembly (single block) ----------------
__global__ __launch_bounds__(256) void reduce_kernel(const double* __restrict__ partials,
                                                     float* __restrict__ out) {
    double s[6] = {0, 0, 0, 0, 0, 0};
    for (int b = threadIdx.x; b < MAIN_BLOCKS; b += 256)
        #pragma unroll
        for (int i = 0; i < 6; ++i) s[i] += partials[b * 6 + i];

    #pragma unroll
    for (int off = 32; off > 0; off >>= 1)
        #pragma unroll
        for (int i = 0; i < 6; ++i) s[i] += __shfl_down(s[i], off);

    __shared__ double red[4][6];
    int lane = threadIdx.x & 63, wid = threadIdx.x >> 6;
    if (lane == 0)
        #pragma unroll
        for (int i = 0; i < 6; ++i) red[wid][i] = s[i];
    __syncthreads();

    if (threadIdx.x == 0) {
        double S[6];
        #pragma unroll
        for (int i = 0; i < 6; ++i)
            S[i] = red[0][i] + red[1][i] + red[2][i] + red[3][i];
        double S_p = S[0], S_t = S[1], S_pt = S[2], S_f = S[3], S_b = S[4], S_bnd = S[5];
        const double N = (double)NPIX;
        double inter = S_pt;
        double card = S_p + S_t;
        double dice_score = (2.0 * inter + 1e-6) / fmax(card + 1e-6, 1e-7);
        double dice = (S_t > 0.0) ? (1.0 - dice_score) : 0.0;
        double focal = S_f / N;
        double bce = S_b / N;
        double pos_ratio = S_t / N;
        double da = 0.7 * (1.0 + pos_ratio);
        double db = 0.3 * (2.0 - pos_ratio);
        double fn = S_t - S_pt;
        double fp = (S_p - S_pt) * 3.0;
        double tversky = 1.0 - (S_pt + 1e-6) / (S_pt + da * fn + db * fp + 1e-6);
        double bnd = S_bnd / N;
        out[0] = (float)(0.35 * dice + 0.25 * focal + 0.15 * bce + 0.15 * tversky + 0.1 * bnd);
    }
}

extern "C" void kernel_launch(void* const* d_in, const int* in_sizes, int n_in,
                              void* d_out, int out_size, void* d_ws, size_t ws_size,
                              hipStream_t stream) {
    const float* inputs  = (const float*)d_in[0];
    const float* targets = (const float*)d_in[1];
    const float* alpha_p = (const float*)d_in[2];
    const float* gamma_p = (const float*)d_in[3];
    float* out = (float*)d_out;

    char* ws = (char*)d_ws;
    double* partials = (double*)ws;                              // MAIN_BLOCKS*6*8 = 96 KiB
    unsigned char* bmask = (unsigned char*)(ws + 131072);        // NPIX bytes

    dim3 bg(16, 16, 32);
    bmask_fused_kernel<<<bg, 256, 0, stream>>>(targets, bmask);

    main_kernel<<<MAIN_BLOCKS, MAIN_THREADS, 0, stream>>>(
        (const float4*)inputs, (const float4*)targets, bmask, alpha_p, gamma_p, partials);

    reduce_kernel<<<1, 256, 0, stream>>>(partials, out);
}

// Round 4
// 72.616 us; speedup vs baseline: 17.6217x; 1.7592x over previous
//
#include <hip/hip_runtime.h>

typedef unsigned long long u64;

#define HH 512
#define WW 512
#define BATCH 32
#define NPIX (BATCH*HH*WW)
#define NQ (NPIX/4)
#define NWORDS (NPIX/64)
#define WPI (HH*WW/64)      /* words per image = 4096 */
#define WPR (WW/64)         /* words per row = 8 */
#define MAIN_BLOCKS 2048
#define MAIN_THREADS 256

__device__ __forceinline__ float hw_exp2(float x) { return __builtin_amdgcn_exp2f(x); }
__device__ __forceinline__ float hw_log2(float x) { return __builtin_amdgcn_logf(x); }

// ---------------- pack targets to 1 bit/pixel ----------------
__global__ __launch_bounds__(256) void pack_kernel(const float* __restrict__ t,
                                                   u64* __restrict__ bits) {
    int stride = gridDim.x * 256;
    for (int i = blockIdx.x * 256 + threadIdx.x; i < NPIX; i += stride) {
        u64 m = __ballot(t[i] > 0.5f);
        if ((threadIdx.x & 63) == 0) bits[i >> 6] = m;
    }
}

// ---------------- bitwise erode -> edge -> dilate ----------------
// eroded = AND over 3x3 (zero pad), edge = t & ~eroded, bmask = OR over 3x3 of edge.
__global__ __launch_bounds__(256) void stencil_kernel(const u64* __restrict__ tb,
                                                      u64* __restrict__ bmbits) {
    int wi = blockIdx.x * 256 + threadIdx.x;
    if (wi >= NWORDS) return;
    int img = wi >> 12;       // /WPI
    int loc = wi & (WPI - 1);
    int y = loc >> 3;         // /WPR
    int wx = loc & (WPR - 1);
    const u64* base = tb + img * WPI;

    u64 w[5][5];
    #pragma unroll
    for (int r = 0; r < 5; ++r) {
        int yy = y + r - 2;
        #pragma unroll
        for (int c = 0; c < 5; ++c) {
            int xx = wx + c - 2;
            w[r][c] = (yy >= 0 && yy < HH && xx >= 0 && xx < WPR) ? base[yy * WPR + xx] : 0ULL;
        }
    }

    // horizontal 3-AND for all 5 rows, word cols 1..3
    u64 ha[5][3];
    #pragma unroll
    for (int r = 0; r < 5; ++r)
        #pragma unroll
        for (int j = 0; j < 3; ++j) {
            u64 C = w[r][j + 1], L = w[r][j], R = w[r][j + 2];
            ha[r][j] = ((C << 1) | (L >> 63)) & C & ((C >> 1) | (R << 63));
        }

    // edge words for rows y-1..y+1, cols wx-1..wx+1
    u64 eg[3][3];
    #pragma unroll
    for (int i = 0; i < 3; ++i)
        #pragma unroll
        for (int j = 0; j < 3; ++j) {
            u64 er = ha[i][j] & ha[i + 1][j] & ha[i + 2][j];
            eg[i][j] = w[i + 1][j + 1] & ~er;
        }

    // horizontal 3-OR on center col, then vertical OR
    u64 out = 0ULL;
    #pragma unroll
    for (int i = 0; i < 3; ++i) {
        u64 E = eg[i][1], L = eg[i][0], R = eg[i][2];
        out |= ((E << 1) | (L >> 63)) | E | ((E >> 1) | (R << 63));
    }
    bmbits[wi] = out;
}

__device__ __forceinline__ int testbit(const u64* __restrict__ bits, int idx) {
    return (int)((bits[idx >> 6] >> (idx & 63)) & 1ULL);
}

// ---------------- fused streaming reductions ----------------
__global__ __launch_bounds__(MAIN_THREADS) void main_kernel(
        const float4* __restrict__ x4, const u64* __restrict__ tbits,
        const u64* __restrict__ bmbits,
        const float* __restrict__ alpha_p, const float* __restrict__ gamma_p,
        double* __restrict__ partials) {
    const float a = fminf(fmaxf(alpha_p[0], 0.1f), 0.9f);
    const float g = fminf(fmaxf(gamma_p[0], 1.0f), 5.0f);
    const float SQ2 = 1.4142135f;
    const float INFD = 10000.0f;
    const float LOGCLIP = 16.11809565f;   // -log(1e-7)
    const float L2E = 1.44269504f;
    const float LN2 = 0.69314718f;

    float s_p = 0.f, s_t = 0.f, s_pt = 0.f, s_f = 0.f, s_b = 0.f, s_bnd = 0.f;

    for (int q = blockIdx.x * MAIN_THREADS + threadIdx.x; q < NQ; q += gridDim.x * MAIN_THREADS) {
        float4 xv4 = x4[q];
        int pix0 = q * 4;
        int sh = pix0 & 63;
        u64 tw = tbits[pix0 >> 6] >> sh;
        u64 bw = bmbits[pix0 >> 6] >> sh;
        float xs[4] = {xv4.x, xv4.y, xv4.z, xv4.w};

        #pragma unroll
        for (int k = 0; k < 4; ++k) {
            float xv = xs[k];
            float tv = (float)((tw >> k) & 1ULL);
            int bm = (int)((bw >> k) & 1ULL);
            int pix = pix0 + k;

            float ax = fabsf(xv);
            float e = hw_exp2(ax * -L2E);             // exp(-|x|)
            float rc = __builtin_amdgcn_rcpf(1.0f + e);
            float p = (xv >= 0.0f) ? rc : e * rc;     // sigmoid
            float l1pe = hw_log2(1.0f + e) * LN2;     // log(1+exp(-|x|))
            float sp_neg = fmaxf(-xv, 0.0f) + l1pe;   // softplus(-x)
            float sp_pos = fmaxf(xv, 0.0f) + l1pe;    // softplus(x)

            float st = tv * 0.95f + 0.025f;
            float bce_el = st * sp_neg + (1.0f - st) * sp_pos;
            float p_t = st * p + (1.0f - st) * (1.0f - p);
            float a_t = st * a + (1.0f - st) * (1.0f - a);
            float u = 1.0f - p_t;                     // in [0.025, 0.975]
            float focal_el = a_t * hw_exp2(g * hw_log2(u)) * bce_el;

            float bce2 = 7.0f * tv * sp_neg + (1.0f - tv) * sp_pos;

            // boundary weight via exact truncated chamfer (early-exit ring search)
            float wgt;
            if (bm) {
                wgt = 1.1f;
            } else {
                int x0 = pix & (WW - 1);
                int y0 = (pix >> 9) & (HH - 1);
                int base = pix - y0 * WW - x0;
                float best = INFD;
                for (int r = 1; r <= 24; ++r) {
                    if (best <= (float)r) break;
                    int ylo = y0 - r, yhi = y0 + r;
                    for (int dx = -r; dx <= r; ++dx) {
                        int xx = x0 + dx;
                        if (xx < 0 || xx >= WW) continue;
                        int mn = abs(dx);
                        float cost = (float)(r - mn) + SQ2 * (float)mn;
                        if (cost < best) {
                            bool hit = false;
                            if (ylo >= 0 && testbit(bmbits, base + ylo * WW + xx)) hit = true;
                            if (yhi < HH && testbit(bmbits, base + yhi * WW + xx)) hit = true;
                            if (hit) best = cost;
                        }
                    }
                    int xlo = x0 - r, xhi = x0 + r;
                    for (int dy = -r + 1; dy <= r - 1; ++dy) {
                        int yy = y0 + dy;
                        if (yy < 0 || yy >= HH) continue;
                        int mn = abs(dy);
                        float cost = (float)(r - mn) + SQ2 * (float)mn;
                        if (cost < best) {
                            bool hit = false;
                            if (xlo >= 0 && testbit(bmbits, base + yy * WW + xlo)) hit = true;
                            if (xhi < WW && testbit(bmbits, base + yy * WW + xhi)) hit = true;
                            if (hit) best = cost;
                        }
                    }
                }
                wgt = hw_exp2(best * (-L2E / 3.0f)) + 0.1f;  // exp(-d/3)+0.1 ; INFD -> 0.1
            }

            // bnd_bce with clip(p,1e-7,1-1e-7) == clamp -log at -log(1e-7)
            float bnd = tv * fminf(sp_neg, LOGCLIP) + (1.0f - tv) * fminf(sp_pos, LOGCLIP);

            s_p   += p;
            s_t   += tv;
            s_pt  += p * tv;
            s_f   += focal_el;
            s_b   += bce2;
            s_bnd += bnd * wgt;
        }
    }

    double d_p = s_p, d_t = s_t, d_pt = s_pt, d_f = s_f, d_b = s_b, d_bnd = s_bnd;

    #pragma unroll
    for (int off = 32; off > 0; off >>= 1) {
        d_p   += __shfl_down(d_p, off);
        d_t   += __shfl_down(d_t, off);
        d_pt  += __shfl_down(d_pt, off);
        d_f   += __shfl_down(d_f, off);
        d_b   += __shfl_down(d_b, off);
        d_bnd += __shfl_down(d_bnd, off);
    }

    __shared__ double red[4][6];
    int lane = threadIdx.x & 63, wid = threadIdx.x >> 6;
    if (lane == 0) {
        red[wid][0] = d_p;  red[wid][1] = d_t;  red[wid][2] = d_pt;
        red[wid][3] = d_f;  red[wid][4] = d_b;  red[wid][5] = d_bnd;
    }
    __syncthreads();
    if (threadIdx.x == 0) {
        #pragma unroll
        for (int i = 0; i < 6; ++i)
            partials[blockIdx.x * 6 + i] = red[0][i] + red[1][i] + red[2][i] + red[3][i];
    }
}

// ---------------- final reduction + loss assembly ----------------
__global__ __launch_bounds__(256) void reduce_kernel(const double* __restrict__ partials,
                                                     float* __restrict__ out) {
    double s[6] = {0, 0, 0, 0, 0, 0};
    for (int b = threadIdx.x; b < MAIN_BLOCKS; b += 256)
        #pragma unroll
        for (int i = 0; i < 6; ++i) s[i] += partials[b * 6 + i];

    #pragma unroll
    for (int off = 32; off > 0; off >>= 1)
        #pragma unroll
        for (int i = 0; i < 6; ++i) s[i] += __shfl_down(s[i], off);

    __shared__ double red[4][6];
    int lane = threadIdx.x & 63, wid = threadIdx.x >> 6;
    if (lane == 0)
        #pragma unroll
        for (int i = 0; i < 6; ++i) red[wid][i] = s[i];
    __syncthreads();

    if (threadIdx.x == 0) {
        double S_p = red[0][0] + red[1][0] + red[2][0] + red[3][0];
        double S_t = red[0][1] + red[1][1] + red[2][1] + red[3][1];
        double S_pt = red[0][2] + red[1][2] + red[2][2] + red[3][2];
        double S_f = red[0][3] + red[1][3] + red[2][3] + red[3][3];
        double S_b = red[0][4] + red[1][4] + red[2][4] + red[3][4];
        double S_bnd = red[0][5] + red[1][5] + red[2][5] + red[3][5];
        const double N = (double)NPIX;
        double inter = S_pt;
        double card = S_p + S_t;
        double dice_score = (2.0 * inter + 1e-6) / fmax(card + 1e-6, 1e-7);
        double dice = (S_t > 0.0) ? (1.0 - dice_score) : 0.0;
        double focal = S_f / N;
        double bce = S_b / N;
        double pos_ratio = S_t / N;
        double da = 0.7 * (1.0 + pos_ratio);
        double db = 0.3 * (2.0 - pos_ratio);
        double fn = S_t - S_pt;
        double fp = (S_p - S_pt) * 3.0;
        double tversky = 1.0 - (S_pt + 1e-6) / (S_pt + da * fn + db * fp + 1e-6);
        double bnd = S_bnd / N;
        out[0] = (float)(0.35 * dice + 0.25 * focal + 0.15 * bce + 0.15 * tversky + 0.1 * bnd);
    }
}

extern "C" void kernel_launch(void* const* d_in, const int* in_sizes, int n_in,
                              void* d_out, int out_size, void* d_ws, size_t ws_size,
                              hipStream_t stream) {
    const float* inputs  = (const float*)d_in[0];
    const float* targets = (const float*)d_in[1];
    const float* alpha_p = (const float*)d_in[2];
    const float* gamma_p = (const float*)d_in[3];
    float* out = (float*)d_out;

    char* ws = (char*)d_ws;
    double* partials = (double*)ws;                     // MAIN_BLOCKS*6*8 = 96 KiB
    u64* tbits  = (u64*)(ws + 131072);                  // NWORDS*8 = 1 MiB
    u64* bmbits = (u64*)(ws + 131072 + NWORDS * 8);     // 1 MiB

    pack_kernel<<<4096, 256, 0, stream>>>(targets, tbits);
    stencil_kernel<<<NWORDS / 256, 256, 0, stream>>>(tbits, bmbits);
    main_kernel<<<MAIN_BLOCKS, MAIN_THREADS, 0, stream>>>(
        (const float4*)inputs, tbits, bmbits, alpha_p, gamma_p, partials);
    reduce_kernel<<<1, 256, 0, stream>>>(partials, out);
}

// Round 5
// 57.575 us; speedup vs baseline: 22.2251x; 1.2612x over previous
//
#include <hip/hip_runtime.h>

typedef unsigned long long u64;

#define HH 512
#define WW 512
#define BATCH 32
#define NPIX (BATCH*HH*WW)
#define NQ (NPIX/4)
#define NWORDS (NPIX/64)
#define WPI (HH*WW/64)      /* words per image = 4096 */
#define WPR (WW/64)         /* words per row = 8 */
#define MAIN_BLOCKS 2048
#define MAIN_THREADS 256
#define PX_PER_BLOCK 4096   /* NPIX / MAIN_BLOCKS */
#define WINMASK ((((1ULL<<49)-1)) << 8)   /* dx in [-24,24] of the 64-bit window */

__device__ __forceinline__ float hw_exp2(float x) { return __builtin_amdgcn_exp2f(x); }
__device__ __forceinline__ float hw_log2(float x) { return __builtin_amdgcn_logf(x); }

// ---------------- pack targets to 1 bit/pixel ----------------
__global__ __launch_bounds__(256) void pack_kernel(const float* __restrict__ t,
                                                   u64* __restrict__ bits) {
    int stride = gridDim.x * 256;
    for (int i = blockIdx.x * 256 + threadIdx.x; i < NPIX; i += stride) {
        u64 m = __ballot(t[i] > 0.5f);
        if ((threadIdx.x & 63) == 0) bits[i >> 6] = m;
    }
}

// ---------------- bitwise erode -> edge -> dilate ----------------
__global__ __launch_bounds__(256) void stencil_kernel(const u64* __restrict__ tb,
                                                      u64* __restrict__ bmbits) {
    int wi = blockIdx.x * 256 + threadIdx.x;
    if (wi >= NWORDS) return;
    int img = wi >> 12;
    int loc = wi & (WPI - 1);
    int y = loc >> 3;
    int wx = loc & (WPR - 1);
    const u64* base = tb + img * WPI;

    u64 w[5][5];
    #pragma unroll
    for (int r = 0; r < 5; ++r) {
        int yy = y + r - 2;
        #pragma unroll
        for (int c = 0; c < 5; ++c) {
            int xx = wx + c - 2;
            w[r][c] = (yy >= 0 && yy < HH && xx >= 0 && xx < WPR) ? base[yy * WPR + xx] : 0ULL;
        }
    }

    u64 ha[5][3];
    #pragma unroll
    for (int r = 0; r < 5; ++r)
        #pragma unroll
        for (int j = 0; j < 3; ++j) {
            u64 C = w[r][j + 1], L = w[r][j], R = w[r][j + 2];
            ha[r][j] = ((C << 1) | (L >> 63)) & C & ((C >> 1) | (R << 63));
        }

    u64 eg[3][3];
    #pragma unroll
    for (int i = 0; i < 3; ++i)
        #pragma unroll
        for (int j = 0; j < 3; ++j) {
            u64 er = ha[i][j] & ha[i + 1][j] & ha[i + 2][j];
            eg[i][j] = w[i + 1][j + 1] & ~er;
        }

    u64 out = 0ULL;
    #pragma unroll
    for (int i = 0; i < 3; ++i) {
        u64 E = eg[i][1], L = eg[i][0], R = eg[i][2];
        out |= ((E << 1) | (L >> 63)) | E | ((E >> 1) | (R << 63));
    }
    bmbits[wi] = out;
}

// nearest set-bit horizontal distance within +/-24 of x0 on one bit-packed row; 99 if none
__device__ __forceinline__ int rowscan(const u64* __restrict__ row, int x0) {
    int s = x0 - 32;
    int wi = s >> 6;          // arithmetic shift = floor for negatives
    int sh = s & 63;
    u64 lo = (wi >= 0 && wi < WPR) ? row[wi] : 0ULL;
    u64 hi = ((wi + 1) < WPR) ? row[wi + 1] : 0ULL;   // wi+1 >= 0 always (wi >= -1)
    u64 win = sh ? ((lo >> sh) | (hi << (64 - sh))) : lo;
    win &= WINMASK;
    u64 left = win << 32;     // dx=-32..-1 -> bits 32..63 (bit63 = dx=-1)
    u64 right = win >> 32;    // dx=0..31  -> bits 0..31
    int dl = left ? (__builtin_clzll(left) + 1) : 99;
    int dr = right ? __builtin_ctzll(right) : 99;
    return dl < dr ? dl : dr;
}

// ---------------- fused streaming reductions + compacted boundary search ----------------
__global__ __launch_bounds__(MAIN_THREADS) void main_kernel(
        const float4* __restrict__ x4, const u64* __restrict__ tbits,
        const u64* __restrict__ bmbits,
        const float* __restrict__ alpha_p, const float* __restrict__ gamma_p,
        double* __restrict__ partials) {
    __shared__ int   qpix[PX_PER_BLOCK];
    __shared__ float qbnd[PX_PER_BLOCK];
    __shared__ int lcount;
    __shared__ double red[4][6];

    if (threadIdx.x == 0) lcount = 0;
    __syncthreads();

    const float a = fminf(fmaxf(alpha_p[0], 0.1f), 0.9f);
    const float g = fminf(fmaxf(gamma_p[0], 1.0f), 5.0f);
    const float LOGCLIP = 16.11809565f;   // -log(1e-7)
    const float L2E = 1.44269504f;
    const float LN2 = 0.69314718f;

    float s_p = 0.f, s_t = 0.f, s_pt = 0.f, s_f = 0.f, s_b = 0.f, s_bnd = 0.f;

    #pragma unroll
    for (int it = 0; it < 4; ++it) {
        int q = (it * MAIN_BLOCKS + blockIdx.x) * MAIN_THREADS + threadIdx.x;
        float4 xv4 = x4[q];
        int pix0 = q * 4;
        int sh = pix0 & 63;
        u64 tw = tbits[pix0 >> 6] >> sh;
        u64 bw = bmbits[pix0 >> 6] >> sh;
        float xs[4] = {xv4.x, xv4.y, xv4.z, xv4.w};

        #pragma unroll
        for (int k = 0; k < 4; ++k) {
            float xv = xs[k];
            float tv = (float)((tw >> k) & 1ULL);
            int bm = (int)((bw >> k) & 1ULL);

            float ax = fabsf(xv);
            float e = hw_exp2(ax * -L2E);             // exp(-|x|)
            float rc = __builtin_amdgcn_rcpf(1.0f + e);
            float p = (xv >= 0.0f) ? rc : e * rc;     // sigmoid
            float l1pe = hw_log2(1.0f + e) * LN2;     // log(1+exp(-|x|))
            float sp_neg = fmaxf(-xv, 0.0f) + l1pe;   // softplus(-x)
            float sp_pos = fmaxf(xv, 0.0f) + l1pe;    // softplus(x)

            float st = tv * 0.95f + 0.025f;
            float bce_el = st * sp_neg + (1.0f - st) * sp_pos;
            float p_t = st * p + (1.0f - st) * (1.0f - p);
            float a_t = st * a + (1.0f - st) * (1.0f - a);
            float u = 1.0f - p_t;
            float focal_el = a_t * hw_exp2(g * hw_log2(u)) * bce_el;

            float bce2 = 7.0f * tv * sp_neg + (1.0f - tv) * sp_pos;
            float bnd = tv * fminf(sp_neg, LOGCLIP) + (1.0f - tv) * fminf(sp_pos, LOGCLIP);

            if (bm) {
                s_bnd += bnd * 1.1f;                  // d=0 -> w = 1 + 0.1
            } else {
                int slot = atomicAdd(&lcount, 1);     // LDS atomic
                qpix[slot] = pix0 + k;
                qbnd[slot] = bnd;
            }

            s_p   += p;
            s_t   += tv;
            s_pt  += p * tv;
            s_f   += focal_el;
            s_b   += bce2;
        }
    }

    __syncthreads();
    int n = lcount;
    for (int j = threadIdx.x; j < n; j += MAIN_THREADS) {
        int pix = qpix[j];
        int x0 = pix & (WW - 1);
        int y0 = (pix >> 9) & (HH - 1);
        const u64* img = bmbits + (pix >> 18) * WPI;
        float best = 1e9f;
        for (int ady = 0; ady <= 24; ++ady) {
            if ((float)ady >= best) break;
            int hd = 99;
            int yU = y0 - ady;
            if (yU >= 0) hd = rowscan(img + yU * WPR, x0);
            int yD = y0 + ady;
            if (ady > 0 && yD < HH) {
                int h2 = rowscan(img + yD * WPR, x0);
                hd = h2 < hd ? h2 : hd;
            }
            if (hd <= 24) {
                float h = (float)hd, ay = (float)ady;
                float mx = fmaxf(h, ay), mn = fminf(h, ay);
                best = fminf(best, mx + 0.4142135f * mn);
            }
        }
        float wgt = (best < 1e8f) ? (hw_exp2(best * (-L2E / 3.0f)) + 0.1f) : 0.1f;
        s_bnd += qbnd[j] * wgt;
    }

    double d_p = s_p, d_t = s_t, d_pt = s_pt, d_f = s_f, d_b = s_b, d_bnd = s_bnd;

    #pragma unroll
    for (int off = 32; off > 0; off >>= 1) {
        d_p   += __shfl_down(d_p, off);
        d_t   += __shfl_down(d_t, off);
        d_pt  += __shfl_down(d_pt, off);
        d_f   += __shfl_down(d_f, off);
        d_b   += __shfl_down(d_b, off);
        d_bnd += __shfl_down(d_bnd, off);
    }

    int lane = threadIdx.x & 63, wid = threadIdx.x >> 6;
    if (lane == 0) {
        red[wid][0] = d_p;  red[wid][1] = d_t;  red[wid][2] = d_pt;
        red[wid][3] = d_f;  red[wid][4] = d_b;  red[wid][5] = d_bnd;
    }
    __syncthreads();
    if (threadIdx.x == 0) {
        #pragma unroll
        for (int i = 0; i < 6; ++i)
            partials[blockIdx.x * 6 + i] = red[0][i] + red[1][i] + red[2][i] + red[3][i];
    }
}

// ---------------- final reduction + loss assembly ----------------
__global__ __launch_bounds__(256) void reduce_kernel(const double* __restrict__ partials,
                                                     float* __restrict__ out) {
    double s[6] = {0, 0, 0, 0, 0, 0};
    for (int b = threadIdx.x; b < MAIN_BLOCKS; b += 256)
        #pragma unroll
        for (int i = 0; i < 6; ++i) s[i] += partials[b * 6 + i];

    #pragma unroll
    for (int off = 32; off > 0; off >>= 1)
        #pragma unroll
        for (int i = 0; i < 6; ++i) s[i] += __shfl_down(s[i], off);

    __shared__ double red[4][6];
    int lane = threadIdx.x & 63, wid = threadIdx.x >> 6;
    if (lane == 0)
        #pragma unroll
        for (int i = 0; i < 6; ++i) red[wid][i] = s[i];
    __syncthreads();

    if (threadIdx.x == 0) {
        double S_p = red[0][0] + red[1][0] + red[2][0] + red[3][0];
        double S_t = red[0][1] + red[1][1] + red[2][1] + red[3][1];
        double S_pt = red[0][2] + red[1][2] + red[2][2] + red[3][2];
        double S_f = red[0][3] + red[1][3] + red[2][3] + red[3][3];
        double S_b = red[0][4] + red[1][4] + red[2][4] + red[3][4];
        double S_bnd = red[0][5] + red[1][5] + red[2][5] + red[3][5];
        const double N = (double)NPIX;
        double inter = S_pt;
        double card = S_p + S_t;
        double dice_score = (2.0 * inter + 1e-6) / fmax(card + 1e-6, 1e-7);
        double dice = (S_t > 0.0) ? (1.0 - dice_score) : 0.0;
        double focal = S_f / N;
        double bce = S_b / N;
        double pos_ratio = S_t / N;
        double da = 0.7 * (1.0 + pos_ratio);
        double db = 0.3 * (2.0 - pos_ratio);
        double fn = S_t - S_pt;
        double fp = (S_p - S_pt) * 3.0;
        double tversky = 1.0 - (S_pt + 1e-6) / (S_pt + da * fn + db * fp + 1e-6);
        double bnd = S_bnd / N;
        out[0] = (float)(0.35 * dice + 0.25 * focal + 0.15 * bce + 0.15 * tversky + 0.1 * bnd);
    }
}

extern "C" void kernel_launch(void* const* d_in, const int* in_sizes, int n_in,
                              void* d_out, int out_size, void* d_ws, size_t ws_size,
                              hipStream_t stream) {
    const float* inputs  = (const float*)d_in[0];
    const float* targets = (const float*)d_in[1];
    const float* alpha_p = (const float*)d_in[2];
    const float* gamma_p = (const float*)d_in[3];
    float* out = (float*)d_out;

    char* ws = (char*)d_ws;
    double* partials = (double*)ws;                     // 96 KiB
    u64* tbits  = (u64*)(ws + 131072);                  // 1 MiB
    u64* bmbits = (u64*)(ws + 131072 + NWORDS * 8);     // 1 MiB

    pack_kernel<<<4096, 256, 0, stream>>>(targets, tbits);
    stencil_kernel<<<NWORDS / 256, 256, 0, stream>>>(tbits, bmbits);
    main_kernel<<<MAIN_BLOCKS, MAIN_THREADS, 0, stream>>>(
        (const float4*)inputs, tbits, bmbits, alpha_p, gamma_p, partials);
    reduce_kernel<<<1, 256, 0, stream>>>(partials, out);
}

// Round 6
// 49.977 us; speedup vs baseline: 25.6039x; 1.1520x over previous
//
#include <hip/hip_runtime.h>

typedef unsigned long long u64;
typedef unsigned int u32;

#define HH 512
#define WW 512
#define BATCH 32
#define NPIX (BATCH*HH*WW)
#define NQ (NPIX/4)
#define NWORDS (NPIX/64)
#define WPI (HH*WW/64)      /* words per image = 4096 */
#define WPR (WW/64)         /* words per row = 8 */
#define MAIN_BLOCKS 4096
#define MAIN_THREADS 256
#define MAIN_IT 2           /* NQ / (MAIN_BLOCKS*MAIN_THREADS) */
#define QCAP 1024           /* LDS queue capacity (8 KiB); expected ~80/block */
#define WINMASK ((((1ULL<<49)-1)) << 8)   /* dx in [-24,24] of the 64-bit window */

__device__ __forceinline__ float hw_exp2(float x) { return __builtin_amdgcn_exp2f(x); }
__device__ __forceinline__ float hw_log2(float x) { return __builtin_amdgcn_logf(x); }

// ---------------- pack targets to 1 bit/pixel ----------------
__global__ __launch_bounds__(256) void pack_kernel(const float* __restrict__ t,
                                                   u64* __restrict__ bits) {
    int stride = gridDim.x * 256;
    for (int i = blockIdx.x * 256 + threadIdx.x; i < NPIX; i += stride) {
        u64 m = __ballot(t[i] > 0.5f);
        if ((threadIdx.x & 63) == 0) bits[i >> 6] = m;
    }
}

// ---------------- bitwise erode -> edge -> dilate ----------------
__global__ __launch_bounds__(256) void stencil_kernel(const u64* __restrict__ tb,
                                                      u64* __restrict__ bmbits) {
    int wi = blockIdx.x * 256 + threadIdx.x;
    if (wi >= NWORDS) return;
    int img = wi >> 12;
    int loc = wi & (WPI - 1);
    int y = loc >> 3;
    int wx = loc & (WPR - 1);
    const u64* base = tb + img * WPI;

    u64 w[5][5];
    #pragma unroll
    for (int r = 0; r < 5; ++r) {
        int yy = y + r - 2;
        #pragma unroll
        for (int c = 0; c < 5; ++c) {
            int xx = wx + c - 2;
            w[r][c] = (yy >= 0 && yy < HH && xx >= 0 && xx < WPR) ? base[yy * WPR + xx] : 0ULL;
        }
    }

    u64 ha[5][3];
    #pragma unroll
    for (int r = 0; r < 5; ++r)
        #pragma unroll
        for (int j = 0; j < 3; ++j) {
            u64 C = w[r][j + 1], L = w[r][j], R = w[r][j + 2];
            ha[r][j] = ((C << 1) | (L >> 63)) & C & ((C >> 1) | (R << 63));
        }

    u64 eg[3][3];
    #pragma unroll
    for (int i = 0; i < 3; ++i)
        #pragma unroll
        for (int j = 0; j < 3; ++j) {
            u64 er = ha[i][j] & ha[i + 1][j] & ha[i + 2][j];
            eg[i][j] = w[i + 1][j + 1] & ~er;
        }

    u64 out = 0ULL;
    #pragma unroll
    for (int i = 0; i < 3; ++i) {
        u64 E = eg[i][1], L = eg[i][0], R = eg[i][2];
        out |= ((E << 1) | (L >> 63)) | E | ((E >> 1) | (R << 63));
    }
    bmbits[wi] = out;
}

// nearest set-bit horizontal distance within +/-24 of x0 on one bit-packed row; 99 if none
__device__ __forceinline__ int rowscan(const u64* __restrict__ row, int x0) {
    int s = x0 - 32;
    int wi = s >> 6;
    int sh = s & 63;
    u64 lo = (wi >= 0 && wi < WPR) ? row[wi] : 0ULL;
    u64 hi = ((wi + 1) < WPR) ? row[wi + 1] : 0ULL;
    u64 win = sh ? ((lo >> sh) | (hi << (64 - sh))) : lo;
    win &= WINMASK;
    u64 left = win << 32;
    u64 right = win >> 32;
    int dl = left ? (__builtin_clzll(left) + 1) : 99;
    int dr = right ? __builtin_ctzll(right) : 99;
    return dl < dr ? dl : dr;
}

// full chamfer weight for one non-boundary pixel
__device__ __forceinline__ float search_weight(const u64* __restrict__ img, int pix) {
    const float L2E = 1.44269504f;
    int x0 = pix & (WW - 1);
    int y0 = (pix >> 9) & (HH - 1);
    float best = 1e9f;
    for (int ady = 0; ady <= 24; ++ady) {
        if ((float)ady >= best) break;
        int hd = 99;
        int yU = y0 - ady;
        if (yU >= 0) hd = rowscan(img + yU * WPR, x0);
        int yD = y0 + ady;
        if (ady > 0 && yD < HH) {
            int h2 = rowscan(img + yD * WPR, x0);
            hd = h2 < hd ? h2 : hd;
        }
        if (hd <= 24) {
            float h = (float)hd, ay = (float)ady;
            float mx = fmaxf(h, ay), mn = fminf(h, ay);
            best = fminf(best, mx + 0.4142135f * mn);
        }
    }
    return (best < 1e8f) ? (hw_exp2(best * (-L2E / 3.0f)) + 0.1f) : 0.1f;
}

// ---------------- fused streaming reductions + compacted boundary search ----------------
__global__ __launch_bounds__(MAIN_THREADS, 6) void main_kernel(
        const float4* __restrict__ x4, const u64* __restrict__ tbits,
        const u64* __restrict__ bmbits,
        const float* __restrict__ alpha_p, const float* __restrict__ gamma_p,
        double* __restrict__ partials) {
    __shared__ u64 qdata[QCAP];
    __shared__ int lcount;
    __shared__ double red[4][6];

    if (threadIdx.x == 0) lcount = 0;
    __syncthreads();

    const float a = fminf(fmaxf(alpha_p[0], 0.1f), 0.9f);
    const float one_m_a = 1.0f - a;
    const float g = fminf(fmaxf(gamma_p[0], 1.0f), 5.0f);
    const float gr = rintf(g);
    const bool gint = (g == gr);
    const int gi = (int)gr;
    const float LOGCLIP = 16.11809565f;   // -log(1e-7)
    const float L2E = 1.44269504f;
    const float LN2 = 0.69314718f;

    float s_p = 0.f, s_pt = 0.f, s_f = 0.f, s_b = 0.f, s_bnd_bm = 0.f, s_bnd_q = 0.f;
    int c_t = 0;

    #pragma unroll 1
    for (int it = 0; it < MAIN_IT; ++it) {
        int q = (it * MAIN_BLOCKS + blockIdx.x) * MAIN_THREADS + threadIdx.x;
        float4 xv4 = x4[q];
        int pix0 = q * 4;
        int sh = pix0 & 63;
        u64 tw = tbits[pix0 >> 6] >> sh;
        u64 bw = bmbits[pix0 >> 6] >> sh;
        float xs[4] = {xv4.x, xv4.y, xv4.z, xv4.w};

        #pragma unroll
        for (int k = 0; k < 4; ++k) {
            float xv = xs[k];
            int tb = (int)((tw >> k) & 1ULL);
            int bm = (int)((bw >> k) & 1ULL);

            float ax = fabsf(xv);
            float e  = hw_exp2(ax * -L2E);             // exp(-|x|)
            float rc = __builtin_amdgcn_rcpf(1.0f + e);
            float p  = (xv >= 0.0f) ? rc : e * rc;     // sigmoid
            float l1pe = hw_log2(1.0f + e) * LN2;      // log(1+exp(-|x|))
            float sp_neg = fmaxf(-xv, 0.0f) + l1pe;    // softplus(-x)
            float sp_pos = sp_neg + xv;                // softplus(x)

            float bce_el = sp_neg + (tb ? 0.025f : 0.975f) * xv;
            float q95 = 0.95f * p;
            float u   = tb ? (0.975f - q95) : (0.025f + q95);   // 1 - p_t
            float a_t = tb ? a : one_m_a;
            float pw;
            if (gint) {
                float u2 = u * u;
                pw = (gi == 1) ? u : (gi == 2) ? u2 : (gi == 3) ? u2 * u
                   : (gi == 4) ? u2 * u2 : u2 * u2 * u;
            } else {
                pw = hw_exp2(g * hw_log2(u));
            }
            float focal_el = a_t * pw * bce_el;

            float bce2 = tb ? 7.0f * sp_neg : sp_pos;
            float bnd  = fminf(tb ? sp_neg : sp_pos, LOGCLIP);

            if (bm) {
                s_bnd_bm += bnd;
            } else {
                int slot = atomicAdd(&lcount, 1);
                if (slot < QCAP) {
                    qdata[slot] = ((u64)(u32)(pix0 + k) << 32) | (u64)__float_as_uint(bnd);
                } else {
                    // cold fallback (queue overflow, ~never): search inline
                    s_bnd_q += bnd * search_weight(bmbits + ((pix0 + k) >> 18) * WPI, pix0 + k);
                }
            }

            s_p  += p;
            c_t  += tb;
            s_pt += tb ? p : 0.0f;
            s_f  += focal_el;
            s_b  += bce2;
        }
    }

    __syncthreads();
    int n = lcount < QCAP ? lcount : QCAP;
    for (int j = threadIdx.x; j < n; j += MAIN_THREADS) {
        u64 v = qdata[j];
        int pix = (int)(v >> 32);
        float bnd = __uint_as_float((u32)v);
        s_bnd_q += bnd * search_weight(bmbits + (pix >> 18) * WPI, pix);
    }

    double d_p = s_p, d_t = (double)c_t, d_pt = s_pt, d_f = s_f, d_b = s_b;
    double d_bnd = (double)s_bnd_bm * 1.1 + (double)s_bnd_q;

    #pragma unroll
    for (int off = 32; off > 0; off >>= 1) {
        d_p   += __shfl_down(d_p, off);
        d_t   += __shfl_down(d_t, off);
        d_pt  += __shfl_down(d_pt, off);
        d_f   += __shfl_down(d_f, off);
        d_b   += __shfl_down(d_b, off);
        d_bnd += __shfl_down(d_bnd, off);
    }

    int lane = threadIdx.x & 63, wid = threadIdx.x >> 6;
    if (lane == 0) {
        red[wid][0] = d_p;  red[wid][1] = d_t;  red[wid][2] = d_pt;
        red[wid][3] = d_f;  red[wid][4] = d_b;  red[wid][5] = d_bnd;
    }
    __syncthreads();
    if (threadIdx.x == 0) {
        #pragma unroll
        for (int i = 0; i < 6; ++i)
            partials[blockIdx.x * 6 + i] = red[0][i] + red[1][i] + red[2][i] + red[3][i];
    }
}

// ---------------- final reduction + loss assembly ----------------
__global__ __launch_bounds__(256) void reduce_kernel(const double* __restrict__ partials,
                                                     float* __restrict__ out) {
    double s[6] = {0, 0, 0, 0, 0, 0};
    for (int b = threadIdx.x; b < MAIN_BLOCKS; b += 256)
        #pragma unroll
        for (int i = 0; i < 6; ++i) s[i] += partials[b * 6 + i];

    #pragma unroll
    for (int off = 32; off > 0; off >>= 1)
        #pragma unroll
        for (int i = 0; i < 6; ++i) s[i] += __shfl_down(s[i], off);

    __shared__ double red[4][6];
    int lane = threadIdx.x & 63, wid = threadIdx.x >> 6;
    if (lane == 0)
        #pragma unroll
        for (int i = 0; i < 6; ++i) red[wid][i] = s[i];
    __syncthreads();

    if (threadIdx.x == 0) {
        double S_p = red[0][0] + red[1][0] + red[2][0] + red[3][0];
        double S_t = red[0][1] + red[1][1] + red[2][1] + red[3][1];
        double S_pt = red[0][2] + red[1][2] + red[2][2] + red[3][2];
        double S_f = red[0][3] + red[1][3] + red[2][3] + red[3][3];
        double S_b = red[0][4] + red[1][4] + red[2][4] + red[3][4];
        double S_bnd = red[0][5] + red[1][5] + red[2][5] + red[3][5];
        const double N = (double)NPIX;
        double inter = S_pt;
        double card = S_p + S_t;
        double dice_score = (2.0 * inter + 1e-6) / fmax(card + 1e-6, 1e-7);
        double dice = (S_t > 0.0) ? (1.0 - dice_score) : 0.0;
        double focal = S_f / N;
        double bce = S_b / N;
        double pos_ratio = S_t / N;
        double da = 0.7 * (1.0 + pos_ratio);
        double db = 0.3 * (2.0 - pos_ratio);
        double fn = S_t - S_pt;
        double fp = (S_p - S_pt) * 3.0;
        double tversky = 1.0 - (S_pt + 1e-6) / (S_pt + da * fn + db * fp + 1e-6);
        double bnd = S_bnd / N;
        out[0] = (float)(0.35 * dice + 0.25 * focal + 0.15 * bce + 0.15 * tversky + 0.1 * bnd);
    }
}

extern "C" void kernel_launch(void* const* d_in, const int* in_sizes, int n_in,
                              void* d_out, int out_size, void* d_ws, size_t ws_size,
                              hipStream_t stream) {
    const float* inputs  = (const float*)d_in[0];
    const float* targets = (const float*)d_in[1];
    const float* alpha_p = (const float*)d_in[2];
    const float* gamma_p = (const float*)d_in[3];
    float* out = (float*)d_out;

    char* ws = (char*)d_ws;
    double* partials = (double*)ws;                     // MAIN_BLOCKS*6*8 = 192 KiB
    u64* tbits  = (u64*)(ws + 262144);                  // 1 MiB
    u64* bmbits = (u64*)(ws + 262144 + NWORDS * 8);     // 1 MiB

    pack_kernel<<<4096, 256, 0, stream>>>(targets, tbits);
    stencil_kernel<<<NWORDS / 256, 256, 0, stream>>>(tbits, bmbits);
    main_kernel<<<MAIN_BLOCKS, MAIN_THREADS, 0, stream>>>(
        (const float4*)inputs, tbits, bmbits, alpha_p, gamma_p, partials);
    reduce_kernel<<<1, 256, 0, stream>>>(partials, out);
}

// Round 7
// 46.991 us; speedup vs baseline: 27.2312x; 1.0636x over previous
//
#include <hip/hip_runtime.h>

typedef unsigned long long u64;
typedef unsigned int u32;

#define HH 512
#define WW 512
#define BATCH 32
#define NPIX (BATCH*HH*WW)
#define NQ (NPIX/4)
#define NBYTES (NPIX/8)
#define NWORDS (NPIX/64)
#define WPI (HH*WW/64)      /* words per image = 4096 */
#define WPR (WW/64)         /* words per row = 8 */
#define MAIN_BLOCKS 4096
#define MAIN_THREADS 256
#define MAIN_IT 2           /* NQ / (MAIN_BLOCKS*MAIN_THREADS) */
#define QCAP 1024           /* LDS queue capacity (8 KiB); expected ~80/block */
#define WINMASK ((((1ULL<<49)-1)) << 8)   /* dx in [-24,24] of the 64-bit window */

__device__ __forceinline__ float hw_exp2(float x) { return __builtin_amdgcn_exp2f(x); }
__device__ __forceinline__ float hw_log2(float x) { return __builtin_amdgcn_logf(x); }

// ---------------- pack targets to 1 bit/pixel (byte-wise, vectorized loads) ----------------
// little-endian: byte i bit b == bit (8i+b) of the overlaying u64 array -> identical layout.
__global__ __launch_bounds__(256) void pack_kernel(const float4* __restrict__ t4,
                                                   unsigned char* __restrict__ bytes) {
    int i = blockIdx.x * 256 + threadIdx.x;      // byte index, NBYTES total
    if (i >= NBYTES) return;
    float4 lo = t4[i * 2];
    float4 hi = t4[i * 2 + 1];
    unsigned b =  (lo.x > 0.5f)        | ((lo.y > 0.5f) << 1)
               | ((lo.z > 0.5f) << 2)  | ((lo.w > 0.5f) << 3)
               | ((hi.x > 0.5f) << 4)  | ((hi.y > 0.5f) << 5)
               | ((hi.z > 0.5f) << 6)  | ((hi.w > 0.5f) << 7);
    bytes[i] = (unsigned char)b;
}

// ---------------- bitwise erode -> edge -> dilate ----------------
__global__ __launch_bounds__(256) void stencil_kernel(const u64* __restrict__ tb,
                                                      u64* __restrict__ bmbits) {
    int wi = blockIdx.x * 256 + threadIdx.x;
    if (wi >= NWORDS) return;
    int img = wi >> 12;
    int loc = wi & (WPI - 1);
    int y = loc >> 3;
    int wx = loc & (WPR - 1);
    const u64* base = tb + img * WPI;

    u64 w[5][5];
    #pragma unroll
    for (int r = 0; r < 5; ++r) {
        int yy = y + r - 2;
        #pragma unroll
        for (int c = 0; c < 5; ++c) {
            int xx = wx + c - 2;
            w[r][c] = (yy >= 0 && yy < HH && xx >= 0 && xx < WPR) ? base[yy * WPR + xx] : 0ULL;
        }
    }

    u64 ha[5][3];
    #pragma unroll
    for (int r = 0; r < 5; ++r)
        #pragma unroll
        for (int j = 0; j < 3; ++j) {
            u64 C = w[r][j + 1], L = w[r][j], R = w[r][j + 2];
            ha[r][j] = ((C << 1) | (L >> 63)) & C & ((C >> 1) | (R << 63));
        }

    u64 eg[3][3];
    #pragma unroll
    for (int i = 0; i < 3; ++i)
        #pragma unroll
        for (int j = 0; j < 3; ++j) {
            u64 er = ha[i][j] & ha[i + 1][j] & ha[i + 2][j];
            eg[i][j] = w[i + 1][j + 1] & ~er;
        }

    u64 out = 0ULL;
    #pragma unroll
    for (int i = 0; i < 3; ++i) {
        u64 E = eg[i][1], L = eg[i][0], R = eg[i][2];
        out |= ((E << 1) | (L >> 63)) | E | ((E >> 1) | (R << 63));
    }
    bmbits[wi] = out;
}

// nearest set-bit horizontal distance within +/-24 of x0 on one bit-packed row; 99 if none
__device__ __forceinline__ int rowscan(const u64* __restrict__ row, int x0) {
    int s = x0 - 32;
    int wi = s >> 6;
    int sh = s & 63;
    u64 lo = (wi >= 0 && wi < WPR) ? row[wi] : 0ULL;
    u64 hi = ((wi + 1) < WPR) ? row[wi + 1] : 0ULL;
    u64 win = sh ? ((lo >> sh) | (hi << (64 - sh))) : lo;
    win &= WINMASK;
    u64 left = win << 32;
    u64 right = win >> 32;
    int dl = left ? (__builtin_clzll(left) + 1) : 99;
    int dr = right ? __builtin_ctzll(right) : 99;
    return dl < dr ? dl : dr;
}

// full chamfer weight for one non-boundary pixel
__device__ __forceinline__ float search_weight(const u64* __restrict__ img, int pix) {
    const float L2E = 1.44269504f;
    int x0 = pix & (WW - 1);
    int y0 = (pix >> 9) & (HH - 1);
    float best = 1e9f;
    for (int ady = 0; ady <= 24; ++ady) {
        if ((float)ady >= best) break;
        int hd = 99;
        int yU = y0 - ady;
        if (yU >= 0) hd = rowscan(img + yU * WPR, x0);
        int yD = y0 + ady;
        if (ady > 0 && yD < HH) {
            int h2 = rowscan(img + yD * WPR, x0);
            hd = h2 < hd ? h2 : hd;
        }
        if (hd <= 24) {
            float h = (float)hd, ay = (float)ady;
            float mx = fmaxf(h, ay), mn = fminf(h, ay);
            best = fminf(best, mx + 0.4142135f * mn);
        }
    }
    return (best < 1e8f) ? (hw_exp2(best * (-L2E / 3.0f)) + 0.1f) : 0.1f;
}

// ---------------- fused streaming reductions + compacted boundary search ----------------
__global__ __launch_bounds__(MAIN_THREADS, 6) void main_kernel(
        const float4* __restrict__ x4, const u64* __restrict__ tbits,
        const u64* __restrict__ bmbits,
        const float* __restrict__ alpha_p, const float* __restrict__ gamma_p,
        double* __restrict__ partials) {
    __shared__ u64 qdata[QCAP];
    __shared__ int lcount;
    __shared__ double red[4][6];

    if (threadIdx.x == 0) lcount = 0;
    __syncthreads();

    const float a = fminf(fmaxf(alpha_p[0], 0.1f), 0.9f);
    const float one_m_a = 1.0f - a;
    const float g = fminf(fmaxf(gamma_p[0], 1.0f), 5.0f);
    const float gr = rintf(g);
    const bool gint = (g == gr);
    const int gi = (int)gr;
    const float LOGCLIP = 16.11809565f;   // -log(1e-7)
    const float L2E = 1.44269504f;
    const float LN2 = 0.69314718f;

    float s_p = 0.f, s_pt = 0.f, s_f = 0.f, s_b = 0.f, s_bnd_bm = 0.f, s_bnd_q = 0.f;
    int c_t = 0;

    #pragma unroll 1
    for (int it = 0; it < MAIN_IT; ++it) {
        int q = (it * MAIN_BLOCKS + blockIdx.x) * MAIN_THREADS + threadIdx.x;
        float4 xv4 = x4[q];
        int pix0 = q * 4;
        int sh = pix0 & 63;
        u64 tw = tbits[pix0 >> 6] >> sh;
        u64 bw = bmbits[pix0 >> 6] >> sh;
        float xs[4] = {xv4.x, xv4.y, xv4.z, xv4.w};

        #pragma unroll
        for (int k = 0; k < 4; ++k) {
            float xv = xs[k];
            int tb = (int)((tw >> k) & 1ULL);
            int bm = (int)((bw >> k) & 1ULL);

            float ax = fabsf(xv);
            float e  = hw_exp2(ax * -L2E);             // exp(-|x|)
            float rc = __builtin_amdgcn_rcpf(1.0f + e);
            float p  = (xv >= 0.0f) ? rc : e * rc;     // sigmoid
            float l1pe = hw_log2(1.0f + e) * LN2;      // log(1+exp(-|x|))
            float sp_neg = fmaxf(-xv, 0.0f) + l1pe;    // softplus(-x)
            float sp_pos = sp_neg + xv;                // softplus(x)

            float bce_el = sp_neg + (tb ? 0.025f : 0.975f) * xv;
            float q95 = 0.95f * p;
            float u   = tb ? (0.975f - q95) : (0.025f + q95);   // 1 - p_t
            float a_t = tb ? a : one_m_a;
            float pw;
            if (gint) {
                float u2 = u * u;
                pw = (gi == 1) ? u : (gi == 2) ? u2 : (gi == 3) ? u2 * u
                   : (gi == 4) ? u2 * u2 : u2 * u2 * u;
            } else {
                pw = hw_exp2(g * hw_log2(u));
            }
            float focal_el = a_t * pw * bce_el;

            float bce2 = tb ? 7.0f * sp_neg : sp_pos;
            float bnd  = fminf(tb ? sp_neg : sp_pos, LOGCLIP);

            if (bm) {
                s_bnd_bm += bnd;
            } else {
                int slot = atomicAdd(&lcount, 1);
                if (slot < QCAP) {
                    qdata[slot] = ((u64)(u32)(pix0 + k) << 32) | (u64)__float_as_uint(bnd);
                } else {
                    // cold fallback (queue overflow, ~never): search inline
                    s_bnd_q += bnd * search_weight(bmbits + ((pix0 + k) >> 18) * WPI, pix0 + k);
                }
            }

            s_p  += p;
            c_t  += tb;
            s_pt += tb ? p : 0.0f;
            s_f  += focal_el;
            s_b  += bce2;
        }
    }

    __syncthreads();
    int n = lcount < QCAP ? lcount : QCAP;
    for (int j = threadIdx.x; j < n; j += MAIN_THREADS) {
        u64 v = qdata[j];
        int pix = (int)(v >> 32);
        float bnd = __uint_as_float((u32)v);
        s_bnd_q += bnd * search_weight(bmbits + (pix >> 18) * WPI, pix);
    }

    double d_p = s_p, d_t = (double)c_t, d_pt = s_pt, d_f = s_f, d_b = s_b;
    double d_bnd = (double)s_bnd_bm * 1.1 + (double)s_bnd_q;

    #pragma unroll
    for (int off = 32; off > 0; off >>= 1) {
        d_p   += __shfl_down(d_p, off);
        d_t   += __shfl_down(d_t, off);
        d_pt  += __shfl_down(d_pt, off);
        d_f   += __shfl_down(d_f, off);
        d_b   += __shfl_down(d_b, off);
        d_bnd += __shfl_down(d_bnd, off);
    }

    int lane = threadIdx.x & 63, wid = threadIdx.x >> 6;
    if (lane == 0) {
        red[wid][0] = d_p;  red[wid][1] = d_t;  red[wid][2] = d_pt;
        red[wid][3] = d_f;  red[wid][4] = d_b;  red[wid][5] = d_bnd;
    }
    __syncthreads();
    if (threadIdx.x == 0) {
        #pragma unroll
        for (int i = 0; i < 6; ++i)
            partials[blockIdx.x * 6 + i] = red[0][i] + red[1][i] + red[2][i] + red[3][i];
    }
}

// ---------------- final reduction + loss assembly ----------------
__global__ __launch_bounds__(256) void reduce_kernel(const double* __restrict__ partials,
                                                     float* __restrict__ out) {
    double s[6] = {0, 0, 0, 0, 0, 0};
    for (int b = threadIdx.x; b < MAIN_BLOCKS; b += 256)
        #pragma unroll
        for (int i = 0; i < 6; ++i) s[i] += partials[b * 6 + i];

    #pragma unroll
    for (int off = 32; off > 0; off >>= 1)
        #pragma unroll
        for (int i = 0; i < 6; ++i) s[i] += __shfl_down(s[i], off);

    __shared__ double red[4][6];
    int lane = threadIdx.x & 63, wid = threadIdx.x >> 6;
    if (lane == 0)
        #pragma unroll
        for (int i = 0; i < 6; ++i) red[wid][i] = s[i];
    __syncthreads();

    if (threadIdx.x == 0) {
        double S_p = red[0][0] + red[1][0] + red[2][0] + red[3][0];
        double S_t = red[0][1] + red[1][1] + red[2][1] + red[3][1];
        double S_pt = red[0][2] + red[1][2] + red[2][2] + red[3][2];
        double S_f = red[0][3] + red[1][3] + red[2][3] + red[3][3];
        double S_b = red[0][4] + red[1][4] + red[2][4] + red[3][4];
        double S_bnd = red[0][5] + red[1][5] + red[2][5] + red[3][5];
        const double N = (double)NPIX;
        double inter = S_pt;
        double card = S_p + S_t;
        double dice_score = (2.0 * inter + 1e-6) / fmax(card + 1e-6, 1e-7);
        double dice = (S_t > 0.0) ? (1.0 - dice_score) : 0.0;
        double focal = S_f / N;
        double bce = S_b / N;
        double pos_ratio = S_t / N;
        double da = 0.7 * (1.0 + pos_ratio);
        double db = 0.3 * (2.0 - pos_ratio);
        double fn = S_t - S_pt;
        double fp = (S_p - S_pt) * 3.0;
        double tversky = 1.0 - (S_pt + 1e-6) / (S_pt + da * fn + db * fp + 1e-6);
        double bnd = S_bnd / N;
        out[0] = (float)(0.35 * dice + 0.25 * focal + 0.15 * bce + 0.15 * tversky + 0.1 * bnd);
    }
}

extern "C" void kernel_launch(void* const* d_in, const int* in_sizes, int n_in,
                              void* d_out, int out_size, void* d_ws, size_t ws_size,
                              hipStream_t stream) {
    const float* inputs  = (const float*)d_in[0];
    const float* targets = (const float*)d_in[1];
    const float* alpha_p = (const float*)d_in[2];
    const float* gamma_p = (const float*)d_in[3];
    float* out = (float*)d_out;

    char* ws = (char*)d_ws;
    double* partials = (double*)ws;                     // MAIN_BLOCKS*6*8 = 192 KiB
    u64* tbits  = (u64*)(ws + 262144);                  // 1 MiB
    u64* bmbits = (u64*)(ws + 262144 + NWORDS * 8);     // 1 MiB

    pack_kernel<<<NBYTES / 256, 256, 0, stream>>>((const float4*)targets,
                                                  (unsigned char*)tbits);
    stencil_kernel<<<NWORDS / 256, 256, 0, stream>>>(tbits, bmbits);
    main_kernel<<<MAIN_BLOCKS, MAIN_THREADS, 0, stream>>>(
        (const float4*)inputs, tbits, bmbits, alpha_p, gamma_p, partials);
    reduce_kernel<<<1, 256, 0, stream>>>(partials, out);
}